// Round 7
// baseline (294.481 us; speedup 1.0000x reference)
//
#include <hip/hip_runtime.h>
#include <cstddef>
#include <cstdint>

#define B_  4
#define N_  1024
#define D_  1024
#define H_  16
#define DH  64
#define M_  4096   // B_*N_

typedef __attribute__((ext_vector_type(4))) float   f32x4;
typedef __attribute__((ext_vector_type(8))) __bf16  bf16x8;
typedef __attribute__((ext_vector_type(4))) __bf16  bf16x4;

#define MFMA(a, b, c) __builtin_amdgcn_mfma_f32_16x16x32_bf16((a), (b), (c), 0, 0, 0)
#define GLDS(gp, lp) __builtin_amdgcn_global_load_lds( \
    (__attribute__((address_space(1))) void*)(gp),     \
    (__attribute__((address_space(3))) void*)(lp), 16, 0, 0)

// ---------------------------------------------------------------------------
// convert: fp32 -> bf16 for x (4Mi) and Wq/Wk/Wv/Wc (4x1Mi). [verified R3]
// ---------------------------------------------------------------------------
__global__ __launch_bounds__(256) void convert_k(
    const float* __restrict__ x,  const float* __restrict__ Wq,
    const float* __restrict__ Wk, const float* __restrict__ Wv,
    const float* __restrict__ Wc,
    __bf16* __restrict__ xb, __bf16* __restrict__ wqkvb,
    __bf16* __restrict__ wcb)
{
    const unsigned u = blockIdx.x * 256u + threadIdx.x;
    const unsigned e = u * 8u;
    const float* src;
    __bf16* dst;
    if (e < 4194304u) { src = x + e; dst = xb + e; }
    else {
        const unsigned t2 = e - 4194304u;
        const unsigned wsel = t2 >> 20;
        const unsigned wo = t2 & 1048575u;
        src = (wsel == 0 ? Wq : wsel == 1 ? Wk : wsel == 2 ? Wv : Wc) + wo;
        dst = (wsel < 3 ? wqkvb + (size_t)wsel * 1048576u : wcb) + wo;
    }
    const float4 f0 = *(const float4*)(src);
    const float4 f1 = *(const float4*)(src + 4);
    bf16x8 r;
    r[0] = (__bf16)f0.x; r[1] = (__bf16)f0.y; r[2] = (__bf16)f0.z; r[3] = (__bf16)f0.w;
    r[4] = (__bf16)f1.x; r[5] = (__bf16)f1.y; r[6] = (__bf16)f1.z; r[7] = (__bf16)f1.w;
    *(bf16x8*)dst = r;
}

// ---------------------------------------------------------------------------
// NT GEMM, bf16 MFMA. [verified R3-R6] HEADS flag: output index permuted to
// [B,H,N,Dh]; store coalescing unchanged.
// ---------------------------------------------------------------------------
template <typename OutT, bool HEADS>
__global__ __launch_bounds__(256, 3) void gemm_nt(
    const __bf16* __restrict__ A, const __bf16* __restrict__ Wb,
    const float* __restrict__ b0, const float* __restrict__ b1,
    const float* __restrict__ b2, OutT* __restrict__ Cb,
    int Nc, int K)
{
    __shared__ __bf16 As[4096];   // 128x32 bf16, frag-ordered
    __shared__ __bf16 Bs[4096];

    const int tid  = threadIdx.x;
    const int w    = tid >> 6;
    const int lane = tid & 63;
    const int quad = lane >> 4;
    const int l15  = lane & 15;
    const int wr   = w >> 1, wc = w & 1;

    const int m0 = blockIdx.y * 128;
    const int n0 = blockIdx.x * 128;
    const int z  = blockIdx.z;

    const __bf16* W    = Wb + (size_t)z * Nc * K;
    const float*  bias = (z == 0) ? b0 : (z == 1) ? b1 : b2;
    OutT*         C    = Cb + (size_t)z * M_ * Nc;

    const int c1 = w * 128 + lane, c2 = c1 + 64;
    const size_t aoff1 = (size_t)(m0 + ((c1 >> 6) * 16) + (c1 & 15)) * K + (((c1 >> 4) & 3) * 8);
    const size_t aoff2 = (size_t)(m0 + ((c2 >> 6) * 16) + (c2 & 15)) * K + (((c2 >> 4) & 3) * 8);
    const size_t boff1 = (size_t)(n0 + ((c1 >> 6) * 16) + (c1 & 15)) * K + (((c1 >> 4) & 3) * 8);
    const size_t boff2 = (size_t)(n0 + ((c2 >> 6) * 16) + (c2 & 15)) * K + (((c2 >> 4) & 3) * 8);
    __bf16* asdst1 = As + w * 1024;
    __bf16* asdst2 = As + w * 1024 + 512;
    __bf16* bsdst1 = Bs + w * 1024;
    __bf16* bsdst2 = Bs + w * 1024 + 512;

    f32x4 acc[4][4];
    #pragma unroll
    for (int i = 0; i < 4; ++i)
        #pragma unroll
        for (int j = 0; j < 4; ++j)
            acc[i][j] = (f32x4){0.f, 0.f, 0.f, 0.f};

    for (int k0 = 0; k0 < K; k0 += 32) {
        GLDS(A + aoff1 + k0, asdst1);
        GLDS(A + aoff2 + k0, asdst2);
        GLDS(W + boff1 + k0, bsdst1);
        GLDS(W + boff2 + k0, bsdst2);
        __syncthreads();

        bf16x8 af[4], bf[4];
        #pragma unroll
        for (int t = 0; t < 4; ++t) {
            af[t] = *(const bf16x8*)(As + ((wr * 4 + t) * 64 + quad * 16 + l15) * 8);
            bf[t] = *(const bf16x8*)(Bs + ((wc * 4 + t) * 64 + quad * 16 + l15) * 8);
        }
        #pragma unroll
        for (int mt = 0; mt < 4; ++mt)
            #pragma unroll
            for (int nt = 0; nt < 4; ++nt)
                acc[mt][nt] = MFMA(af[mt], bf[nt], acc[mt][nt]);
        __syncthreads();
    }

    float bv[4];
    #pragma unroll
    for (int nt = 0; nt < 4; ++nt)
        bv[nt] = bias[n0 + wc * 64 + nt * 16 + l15];
    #pragma unroll
    for (int mt = 0; mt < 4; ++mt) {
        #pragma unroll
        for (int r = 0; r < 4; ++r) {
            const int row = m0 + wr * 64 + mt * 16 + quad * 4 + r;
            #pragma unroll
            for (int nt = 0; nt < 4; ++nt) {
                const int col = n0 + wc * 64 + nt * 16 + l15;
                const float val = acc[mt][nt][r] + bv[nt];
                if (HEADS) {
                    const size_t idx = (((size_t)(row >> 10) * H_ + (col >> 6)) * N_
                                        + (row & 1023)) * DH + (col & 63);
                    C[idx] = (OutT)val;
                } else {
                    C[(size_t)row * Nc + col] = (OutT)val;
                }
            }
        }
    }
}

// ---------------------------------------------------------------------------
// V transpose: v [B,H,N,Dh] bf16 -> vT [B,H,Dh,N] bf16. [verified R6]
// ---------------------------------------------------------------------------
__global__ __launch_bounds__(256) void transpose_v(
    const __bf16* __restrict__ v, __bf16* __restrict__ vT)
{
    __shared__ __bf16 Ts[64][72];
    const int tid = threadIdx.x;
    const int b  = blockIdx.x >> 8;
    const int h  = (blockIdx.x >> 4) & 15;
    const int nt = blockIdx.x & 15;
    const int r  = tid >> 2;
    const int c0 = (tid & 3) * 16;

    const __bf16* src = v + ((size_t)(b * H_ + h) * N_ + nt * 64 + r) * DH + c0;
    *(bf16x8*)&Ts[r][c0]     = *(const bf16x8*)(src);
    *(bf16x8*)&Ts[r][c0 + 8] = *(const bf16x8*)(src + 8);
    __syncthreads();

    const int dh = tid >> 2;
    __bf16* dst = vT + ((size_t)(b * H_ + h) * DH + dh) * N_ + nt * 64 + c0;
    bf16x8 o0, o1;
    #pragma unroll
    for (int j = 0; j < 8; ++j) o0[j] = Ts[c0 + j][dh];
    #pragma unroll
    for (int j = 0; j < 8; ++j) o1[j] = Ts[c0 + 8 + j][dh];
    *(bf16x8*)dst       = o0;
    *(bf16x8*)(dst + 8) = o1;
}

// ---------------------------------------------------------------------------
// MFMA flash attention v4 — byte-identical to R6 EXCEPT __launch_bounds__
// (256,4): grid gives exactly 4 blocks/CU = 4 waves/SIMD, so declare it and
// get a ~128-VGPR budget. R6's VGPR_Count=52 proved the allocator was
// serializing all 16 fragment loads per iteration at full memory latency
// (the 293k-cycle wall == 16x16 serialized latencies; MFMA/VALU/HBM all idle).
// With 128 VGPRs the 16 frags (64 VGPRs) can sit in flight per iteration.
// ---------------------------------------------------------------------------
#define SP  68
#define SC2 0.04508422f   // (1/32) * log2(e)

__global__ __launch_bounds__(256, 4) void attn_mfma(
    const __bf16* __restrict__ qh, const __bf16* __restrict__ kh,
    const __bf16* __restrict__ vT, __bf16* __restrict__ ob)
{
    __shared__ float Ps[4][16 * SP];   // per-wave P tile, 17408 B total

    const int tid  = threadIdx.x;
    const int w    = tid >> 6;
    const int lane = tid & 63;
    const int quad = lane >> 4;
    const int l15  = lane & 15;

    const int bh = blockIdx.x & 63;   // qt-major: all qt of one head -> same XCD
    const int qt = blockIdx.x >> 6;
    const int b  = bh >> 4;
    const int h  = bh & 15;

    // Q A-frags: m = l15, k = quad*8+j (+32 for qf1)   [B,H,N,Dh] layout
    const __bf16* qp = qh + ((size_t)(b * H_ + h) * N_ + qt * 64 + w * 16 + l15) * DH + quad * 8;
    const bf16x8 qf0 = *(const bf16x8*)(qp);
    const bf16x8 qf1 = *(const bf16x8*)(qp + 32);

    // K B-frag base: n = key = l15 (+ kt*64 + nt*16), k = dh = quad*8+j
    const __bf16* kb = kh + ((size_t)(b * H_ + h) * N_ + l15) * DH + quad * 8;
    // V^T B-frag base: n = dh = l15 (+ nt*16), k = key = quad*8+j (+ kt*64 + kw*32)
    const __bf16* vb = vT + ((size_t)(b * H_ + h) * DH + l15) * N_ + quad * 8;

    float psum[4] = {0.f, 0.f, 0.f, 0.f};
    f32x4 Ov[4];
    #pragma unroll
    for (int nt = 0; nt < 4; ++nt) Ov[nt] = (f32x4){0.f, 0.f, 0.f, 0.f};

    for (int kt = 0; kt < 16; ++kt) {
        // ---- this tile's loads (coalesced 1KB wave-loads; now batchable) ----
        bf16x8 kf0[4], kf1[4], vf[2][4];
        #pragma unroll
        for (int nt = 0; nt < 4; ++nt) {
            const __bf16* kp = kb + (size_t)(kt * 64 + nt * 16) * DH;
            kf0[nt] = *(const bf16x8*)(kp);
            kf1[nt] = *(const bf16x8*)(kp + 32);
        }
        #pragma unroll
        for (int kw = 0; kw < 2; ++kw)
            #pragma unroll
            for (int nt = 0; nt < 4; ++nt)
                vf[kw][nt] = *(const bf16x8*)(vb + (size_t)(nt * 16) * N_ + kt * 64 + kw * 32);

        // ---- S = Q K^T ----
        f32x4 sa[4];
        #pragma unroll
        for (int nt = 0; nt < 4; ++nt) {
            sa[nt] = (f32x4){0.f, 0.f, 0.f, 0.f};
            sa[nt] = MFMA(qf0, kf0[nt], sa[nt]);
            sa[nt] = MFMA(qf1, kf1[nt], sa[nt]);
        }

        // ---- p = exp2(s*c); per-lane row sums; P -> LDS ----
        #pragma unroll
        for (int nt = 0; nt < 4; ++nt) {
            #pragma unroll
            for (int r = 0; r < 4; ++r) {
                const float p = __builtin_exp2f(sa[nt][r] * SC2);
                psum[r] += p;
                Ps[w][(quad * 4 + r) * SP + nt * 16 + l15] = p;
            }
        }
        // same-wave LDS write->read: DS pipe in-order per wave, no barrier.

        // ---- O += P V ----
        #pragma unroll
        for (int kw = 0; kw < 2; ++kw) {
            const f32x4 pa = *(const f32x4*)&Ps[w][l15 * SP + kw * 32 + quad * 8];
            const f32x4 pb = *(const f32x4*)&Ps[w][l15 * SP + kw * 32 + quad * 8 + 4];
            bf16x8 pf;
            #pragma unroll
            for (int j = 0; j < 4; ++j) { pf[j] = (__bf16)pa[j]; pf[4 + j] = (__bf16)pb[j]; }
            #pragma unroll
            for (int nt = 0; nt < 4; ++nt)
                Ov[nt] = MFMA(pf, vf[kw][nt], Ov[nt]);
        }
    }

    // ---- single butterfly reduction of row sums (within 16-lane groups) ----
    float lrow[4];
    #pragma unroll
    for (int r = 0; r < 4; ++r) {
        float lt = psum[r];
        lt += __shfl_xor(lt, 1);
        lt += __shfl_xor(lt, 2);
        lt += __shfl_xor(lt, 4);
        lt += __shfl_xor(lt, 8);
        lrow[r] = lt;
    }

    // ---- epilogue: O /= l, write [B,H,N,Dh]-contiguous bf16 ----
    #pragma unroll
    for (int r = 0; r < 4; ++r) {
        const float inv = 1.0f / lrow[r];
        const int row = qt * 64 + w * 16 + quad * 4 + r;
        __bf16* op = ob + ((size_t)(b * H_ + h) * N_ + row) * DH + l15;
        #pragma unroll
        for (int nt = 0; nt < 4; ++nt)
            op[nt * 16] = (__bf16)(Ov[nt][r] * inv);
    }
}

// ---------------------------------------------------------------------------
extern "C" void kernel_launch(void* const* d_in, const int* in_sizes, int n_in,
                              void* d_out, int out_size, void* d_ws, size_t ws_size,
                              hipStream_t stream) {
    const float* x  = (const float*)d_in[0];
    const float* Wq = (const float*)d_in[1];
    const float* bq = (const float*)d_in[2];
    const float* Wk = (const float*)d_in[3];
    const float* bk = (const float*)d_in[4];
    const float* Wv = (const float*)d_in[5];
    const float* bv = (const float*)d_in[6];
    const float* Wc = (const float*)d_in[7];
    const float* bc = (const float*)d_in[8];
    float* out = (float*)d_out;

    // ws layout (48 MB total):
    //   [ 0, 8MB): xb (bf16 4Mi) -- dead after QKV GEMM, reused as obf
    //   [ 8,14MB): wqkvb  [14,16MB): wcb
    //   [16,40MB): qkvb (bf16 12Mi, each slab [B,H,N,Dh])  [40,48MB): vT
    char* base = (char*)d_ws;
    __bf16* xb    = (__bf16*)(base);
    __bf16* wqkvb = (__bf16*)(base + (size_t)8  * 1048576);
    __bf16* wcb   = (__bf16*)(base + (size_t)14 * 1048576);
    __bf16* qkvb  = (__bf16*)(base + (size_t)16 * 1048576);
    __bf16* vTb   = (__bf16*)(base + (size_t)40 * 1048576);
    __bf16* obf   = (__bf16*)(base);   // overwrites xb after attn

    __bf16* qhb = qkvb;
    __bf16* khb = qkvb + (size_t)M_ * D_;
    __bf16* vhb = qkvb + (size_t)2 * M_ * D_;

    convert_k<<<dim3(4096), dim3(256), 0, stream>>>(
        x, Wq, Wk, Wv, Wc, xb, wqkvb, wcb);

    gemm_nt<__bf16, true><<<dim3(8, 32, 3), dim3(256), 0, stream>>>(
        xb, wqkvb, bq, bk, bv, qkvb, D_, D_);

    transpose_v<<<dim3(1024), dim3(256), 0, stream>>>(vhb, vTb);

    attn_mfma<<<dim3(1024), dim3(256), 0, stream>>>(qhb, khb, vTb, obf);

    gemm_nt<float, false><<<dim3(8, 32, 1), dim3(256), 0, stream>>>(
        obf, wcb, bc, bc, bc, out, D_, D_);
}

// Round 8
// 218.170 us; speedup vs baseline: 1.3498x; 1.3498x over previous
//
#include <hip/hip_runtime.h>
#include <cstddef>
#include <cstdint>

#define B_  4
#define N_  1024
#define D_  1024
#define H_  16
#define DH  64
#define M_  4096   // B_*N_

typedef __attribute__((ext_vector_type(4))) float   f32x4;
typedef __attribute__((ext_vector_type(8))) __bf16  bf16x8;
typedef __attribute__((ext_vector_type(4))) __bf16  bf16x4;

#define MFMA(a, b, c) __builtin_amdgcn_mfma_f32_16x16x32_bf16((a), (b), (c), 0, 0, 0)
#define GLDS(gp, lp) __builtin_amdgcn_global_load_lds( \
    (__attribute__((address_space(1))) void*)(gp),     \
    (__attribute__((address_space(3))) void*)(lp), 16, 0, 0)

// ---------------------------------------------------------------------------
// convert: fp32 -> bf16 for x (4Mi) and Wq/Wk/Wv/Wc (4x1Mi). [verified R3]
// ---------------------------------------------------------------------------
__global__ __launch_bounds__(256) void convert_k(
    const float* __restrict__ x,  const float* __restrict__ Wq,
    const float* __restrict__ Wk, const float* __restrict__ Wv,
    const float* __restrict__ Wc,
    __bf16* __restrict__ xb, __bf16* __restrict__ wqkvb,
    __bf16* __restrict__ wcb)
{
    const unsigned u = blockIdx.x * 256u + threadIdx.x;
    const unsigned e = u * 8u;
    const float* src;
    __bf16* dst;
    if (e < 4194304u) { src = x + e; dst = xb + e; }
    else {
        const unsigned t2 = e - 4194304u;
        const unsigned wsel = t2 >> 20;
        const unsigned wo = t2 & 1048575u;
        src = (wsel == 0 ? Wq : wsel == 1 ? Wk : wsel == 2 ? Wv : Wc) + wo;
        dst = (wsel < 3 ? wqkvb + (size_t)wsel * 1048576u : wcb) + wo;
    }
    const float4 f0 = *(const float4*)(src);
    const float4 f1 = *(const float4*)(src + 4);
    bf16x8 r;
    r[0] = (__bf16)f0.x; r[1] = (__bf16)f0.y; r[2] = (__bf16)f0.z; r[3] = (__bf16)f0.w;
    r[4] = (__bf16)f1.x; r[5] = (__bf16)f1.y; r[6] = (__bf16)f1.z; r[7] = (__bf16)f1.w;
    *(bf16x8*)dst = r;
}

// ---------------------------------------------------------------------------
// NT GEMM, bf16 MFMA. [verified R3-R7] HEADS flag: output index permuted to
// [B,H,N,Dh]; store coalescing unchanged.
// ---------------------------------------------------------------------------
template <typename OutT, bool HEADS>
__global__ __launch_bounds__(256, 3) void gemm_nt(
    const __bf16* __restrict__ A, const __bf16* __restrict__ Wb,
    const float* __restrict__ b0, const float* __restrict__ b1,
    const float* __restrict__ b2, OutT* __restrict__ Cb,
    int Nc, int K)
{
    __shared__ __bf16 As[4096];   // 128x32 bf16, frag-ordered
    __shared__ __bf16 Bs[4096];

    const int tid  = threadIdx.x;
    const int w    = tid >> 6;
    const int lane = tid & 63;
    const int quad = lane >> 4;
    const int l15  = lane & 15;
    const int wr   = w >> 1, wc = w & 1;

    const int m0 = blockIdx.y * 128;
    const int n0 = blockIdx.x * 128;
    const int z  = blockIdx.z;

    const __bf16* W    = Wb + (size_t)z * Nc * K;
    const float*  bias = (z == 0) ? b0 : (z == 1) ? b1 : b2;
    OutT*         C    = Cb + (size_t)z * M_ * Nc;

    const int c1 = w * 128 + lane, c2 = c1 + 64;
    const size_t aoff1 = (size_t)(m0 + ((c1 >> 6) * 16) + (c1 & 15)) * K + (((c1 >> 4) & 3) * 8);
    const size_t aoff2 = (size_t)(m0 + ((c2 >> 6) * 16) + (c2 & 15)) * K + (((c2 >> 4) & 3) * 8);
    const size_t boff1 = (size_t)(n0 + ((c1 >> 6) * 16) + (c1 & 15)) * K + (((c1 >> 4) & 3) * 8);
    const size_t boff2 = (size_t)(n0 + ((c2 >> 6) * 16) + (c2 & 15)) * K + (((c2 >> 4) & 3) * 8);
    __bf16* asdst1 = As + w * 1024;
    __bf16* asdst2 = As + w * 1024 + 512;
    __bf16* bsdst1 = Bs + w * 1024;
    __bf16* bsdst2 = Bs + w * 1024 + 512;

    f32x4 acc[4][4];
    #pragma unroll
    for (int i = 0; i < 4; ++i)
        #pragma unroll
        for (int j = 0; j < 4; ++j)
            acc[i][j] = (f32x4){0.f, 0.f, 0.f, 0.f};

    for (int k0 = 0; k0 < K; k0 += 32) {
        GLDS(A + aoff1 + k0, asdst1);
        GLDS(A + aoff2 + k0, asdst2);
        GLDS(W + boff1 + k0, bsdst1);
        GLDS(W + boff2 + k0, bsdst2);
        __syncthreads();

        bf16x8 af[4], bf[4];
        #pragma unroll
        for (int t = 0; t < 4; ++t) {
            af[t] = *(const bf16x8*)(As + ((wr * 4 + t) * 64 + quad * 16 + l15) * 8);
            bf[t] = *(const bf16x8*)(Bs + ((wc * 4 + t) * 64 + quad * 16 + l15) * 8);
        }
        #pragma unroll
        for (int mt = 0; mt < 4; ++mt)
            #pragma unroll
            for (int nt = 0; nt < 4; ++nt)
                acc[mt][nt] = MFMA(af[mt], bf[nt], acc[mt][nt]);
        __syncthreads();
    }

    float bv[4];
    #pragma unroll
    for (int nt = 0; nt < 4; ++nt)
        bv[nt] = bias[n0 + wc * 64 + nt * 16 + l15];
    #pragma unroll
    for (int mt = 0; mt < 4; ++mt) {
        #pragma unroll
        for (int r = 0; r < 4; ++r) {
            const int row = m0 + wr * 64 + mt * 16 + quad * 4 + r;
            #pragma unroll
            for (int nt = 0; nt < 4; ++nt) {
                const int col = n0 + wc * 64 + nt * 16 + l15;
                const float val = acc[mt][nt][r] + bv[nt];
                if (HEADS) {
                    const size_t idx = (((size_t)(row >> 10) * H_ + (col >> 6)) * N_
                                        + (row & 1023)) * DH + (col & 63);
                    C[idx] = (OutT)val;
                } else {
                    C[(size_t)row * Nc + col] = (OutT)val;
                }
            }
        }
    }
}

// ---------------------------------------------------------------------------
// V transpose: v [B,H,N,Dh] bf16 -> vT [B,H,Dh,N] bf16. [verified R6/R7]
// ---------------------------------------------------------------------------
__global__ __launch_bounds__(256) void transpose_v(
    const __bf16* __restrict__ v, __bf16* __restrict__ vT)
{
    __shared__ __bf16 Ts[64][72];
    const int tid = threadIdx.x;
    const int b  = blockIdx.x >> 8;
    const int h  = (blockIdx.x >> 4) & 15;
    const int nt = blockIdx.x & 15;
    const int r  = tid >> 2;
    const int c0 = (tid & 3) * 16;

    const __bf16* src = v + ((size_t)(b * H_ + h) * N_ + nt * 64 + r) * DH + c0;
    *(bf16x8*)&Ts[r][c0]     = *(const bf16x8*)(src);
    *(bf16x8*)&Ts[r][c0 + 8] = *(const bf16x8*)(src + 8);
    __syncthreads();

    const int dh = tid >> 2;
    __bf16* dst = vT + ((size_t)(b * H_ + h) * DH + dh) * N_ + nt * 64 + c0;
    bf16x8 o0, o1;
    #pragma unroll
    for (int j = 0; j < 8; ++j) o0[j] = Ts[c0 + j][dh];
    #pragma unroll
    for (int j = 0; j < 8; ++j) o1[j] = Ts[c0 + 8 + j][dh];
    *(bf16x8*)dst       = o0;
    *(bf16x8*)(dst + 8) = o1;
}

// ---------------------------------------------------------------------------
// MFMA flash attention v5 — K/V tiles staged into LDS in FRAGMENT ORDER via
// global_load_lds (the R3-verified GEMM staging pattern), replacing R4-R7's
// direct-global fragment loads, which serialized at full memory latency (4
// structurally different variants all pinned at 122 us; VGPR allocator sinks
// loads next to uses regardless of budget/hints). ds_read_b128 frag reads
// pipeline with fine lgkmcnt (m97-proven).
// Chunk decode (512 chunks of 16B per 64x64 tile): c = nt*128 + ko*16 + l
//   K:  global elem off = (nt*16+l)*64  + ko*8   (head-major [key][dh])
//   vT: global elem off = (nt*16+l)*1024 + ko*8  ([dh][key], dh=nt*16+l)
// Frag reads: kf0[nt]=chunk nt*128+quad*16+l15, kf1: +64 chunks;
//   vf[kw][nt]=chunk nt*128+(kw*4+quad)*16+l15. All 1KB-contiguous per wave.
// Softmax single-pass exp2 (verified R5); P LDS round-trip (verified R4).
// ---------------------------------------------------------------------------
#define SP  68
#define SC2 0.04508422f   // (1/32) * log2(e)

__global__ __launch_bounds__(256, 4) void attn_mfma(
    const __bf16* __restrict__ qh, const __bf16* __restrict__ kh,
    const __bf16* __restrict__ vT, __bf16* __restrict__ ob)
{
    __shared__ __bf16 Ks[4096];        // 64 keys x 64 dh, frag-ordered (8KB)
    __shared__ __bf16 Vs[4096];        // 64 dh x 64 keys, frag-ordered (8KB)
    __shared__ float  Ps[4][16 * SP];  // per-wave P tile (17408B); total 33.8KB

    const int tid  = threadIdx.x;
    const int w    = tid >> 6;
    const int lane = tid & 63;
    const int quad = lane >> 4;
    const int l15  = lane & 15;

    const int bh = blockIdx.x & 63;   // qt-major: all qt of one head -> same XCD
    const int qt = blockIdx.x >> 6;
    const int b  = bh >> 4;
    const int h  = bh & 15;

    // Q A-frags: m = l15, k = quad*8+j (+32 for qf1)   [B,H,N,Dh] layout
    const __bf16* qp = qh + ((size_t)(b * H_ + h) * N_ + qt * 64 + w * 16 + l15) * DH + quad * 8;
    const bf16x8 qf0 = *(const bf16x8*)(qp);
    const bf16x8 qf1 = *(const bf16x8*)(qp + 32);

    // ---- staging decode: chunks c1 = tid (wave-contiguous), c2 = tid+256 ----
    const int c1 = tid, c2 = tid + 256;
    const int nt1 = c1 >> 7, ko1 = (c1 >> 4) & 7, l1 = c1 & 15;
    const int nt2 = c2 >> 7, ko2 = (c2 >> 4) & 7, l2 = c2 & 15;
    const __bf16* khead = kh + (size_t)(b * H_ + h) * N_ * DH;
    const __bf16* vhead = vT + (size_t)(b * H_ + h) * DH * N_;
    const size_t koff1 = (size_t)(nt1 * 16 + l1) * DH + ko1 * 8;
    const size_t koff2 = (size_t)(nt2 * 16 + l2) * DH + ko2 * 8;
    const size_t voff1 = (size_t)(nt1 * 16 + l1) * N_ + ko1 * 8;
    const size_t voff2 = (size_t)(nt2 * 16 + l2) * N_ + ko2 * 8;
    __bf16* ksdst1 = Ks + w * 512;            // wave-uniform LDS bases
    __bf16* ksdst2 = Ks + 2048 + w * 512;
    __bf16* vsdst1 = Vs + w * 512;
    __bf16* vsdst2 = Vs + 2048 + w * 512;

    float psum[4] = {0.f, 0.f, 0.f, 0.f};
    f32x4 Ov[4];
    #pragma unroll
    for (int nt = 0; nt < 4; ++nt) Ov[nt] = (f32x4){0.f, 0.f, 0.f, 0.f};

    for (int kt = 0; kt < 16; ++kt) {
        // ---- stage K and V^T tiles (frag order, async) ----
        GLDS(khead + (size_t)kt * 64 * DH + koff1, ksdst1);
        GLDS(khead + (size_t)kt * 64 * DH + koff2, ksdst2);
        GLDS(vhead + (size_t)kt * 64 + voff1, vsdst1);
        GLDS(vhead + (size_t)kt * 64 + voff2, vsdst2);
        __syncthreads();

        // ---- S = Q K^T (frags from LDS) ----
        f32x4 sa[4];
        #pragma unroll
        for (int nt = 0; nt < 4; ++nt) {
            const bf16x8 kf0 = *(const bf16x8*)(Ks + (nt * 128 + quad * 16 + l15) * 8);
            const bf16x8 kf1 = *(const bf16x8*)(Ks + (nt * 128 + (quad + 4) * 16 + l15) * 8);
            sa[nt] = (f32x4){0.f, 0.f, 0.f, 0.f};
            sa[nt] = MFMA(qf0, kf0, sa[nt]);
            sa[nt] = MFMA(qf1, kf1, sa[nt]);
        }

        // ---- p = exp2(s*c); per-lane row sums; P -> LDS ----
        #pragma unroll
        for (int nt = 0; nt < 4; ++nt) {
            #pragma unroll
            for (int r = 0; r < 4; ++r) {
                const float p = __builtin_exp2f(sa[nt][r] * SC2);
                psum[r] += p;
                Ps[w][(quad * 4 + r) * SP + nt * 16 + l15] = p;
            }
        }
        // same-wave LDS write->read: DS pipe in-order per wave, no barrier.

        // ---- O += P V (P from LDS A-layout; V frags from LDS) ----
        #pragma unroll
        for (int kw = 0; kw < 2; ++kw) {
            const f32x4 pa = *(const f32x4*)&Ps[w][l15 * SP + kw * 32 + quad * 8];
            const f32x4 pb = *(const f32x4*)&Ps[w][l15 * SP + kw * 32 + quad * 8 + 4];
            bf16x8 pf;
            #pragma unroll
            for (int j = 0; j < 4; ++j) { pf[j] = (__bf16)pa[j]; pf[4 + j] = (__bf16)pb[j]; }
            #pragma unroll
            for (int nt = 0; nt < 4; ++nt) {
                const bf16x8 vf = *(const bf16x8*)(Vs + (nt * 128 + (kw * 4 + quad) * 16 + l15) * 8);
                Ov[nt] = MFMA(pf, vf, Ov[nt]);
            }
        }
        __syncthreads();   // all waves done reading Ks/Vs before next staging
    }

    // ---- single butterfly reduction of row sums (within 16-lane groups) ----
    float lrow[4];
    #pragma unroll
    for (int r = 0; r < 4; ++r) {
        float lt = psum[r];
        lt += __shfl_xor(lt, 1);
        lt += __shfl_xor(lt, 2);
        lt += __shfl_xor(lt, 4);
        lt += __shfl_xor(lt, 8);
        lrow[r] = lt;
    }

    // ---- epilogue: O /= l, write [B,H,N,Dh]-contiguous bf16 ----
    #pragma unroll
    for (int r = 0; r < 4; ++r) {
        const float inv = 1.0f / lrow[r];
        const int row = qt * 64 + w * 16 + quad * 4 + r;
        __bf16* op = ob + ((size_t)(b * H_ + h) * N_ + row) * DH + l15;
        #pragma unroll
        for (int nt = 0; nt < 4; ++nt)
            op[nt * 16] = (__bf16)(Ov[nt][r] * inv);
    }
}

// ---------------------------------------------------------------------------
extern "C" void kernel_launch(void* const* d_in, const int* in_sizes, int n_in,
                              void* d_out, int out_size, void* d_ws, size_t ws_size,
                              hipStream_t stream) {
    const float* x  = (const float*)d_in[0];
    const float* Wq = (const float*)d_in[1];
    const float* bq = (const float*)d_in[2];
    const float* Wk = (const float*)d_in[3];
    const float* bk = (const float*)d_in[4];
    const float* Wv = (const float*)d_in[5];
    const float* bv = (const float*)d_in[6];
    const float* Wc = (const float*)d_in[7];
    const float* bc = (const float*)d_in[8];
    float* out = (float*)d_out;

    // ws layout (48 MB total):
    //   [ 0, 8MB): xb (bf16 4Mi) -- dead after QKV GEMM, reused as obf
    //   [ 8,14MB): wqkvb  [14,16MB): wcb
    //   [16,40MB): qkvb (bf16 12Mi, each slab [B,H,N,Dh])  [40,48MB): vT
    char* base = (char*)d_ws;
    __bf16* xb    = (__bf16*)(base);
    __bf16* wqkvb = (__bf16*)(base + (size_t)8  * 1048576);
    __bf16* wcb   = (__bf16*)(base + (size_t)14 * 1048576);
    __bf16* qkvb  = (__bf16*)(base + (size_t)16 * 1048576);
    __bf16* vTb   = (__bf16*)(base + (size_t)40 * 1048576);
    __bf16* obf   = (__bf16*)(base);   // overwrites xb after attn

    __bf16* qhb = qkvb;
    __bf16* khb = qkvb + (size_t)M_ * D_;
    __bf16* vhb = qkvb + (size_t)2 * M_ * D_;

    convert_k<<<dim3(4096), dim3(256), 0, stream>>>(
        x, Wq, Wk, Wv, Wc, xb, wqkvb, wcb);

    gemm_nt<__bf16, true><<<dim3(8, 32, 3), dim3(256), 0, stream>>>(
        xb, wqkvb, bq, bk, bv, qkvb, D_, D_);

    transpose_v<<<dim3(1024), dim3(256), 0, stream>>>(vhb, vTb);

    attn_mfma<<<dim3(1024), dim3(256), 0, stream>>>(qhb, khb, vTb, obf);

    gemm_nt<float, false><<<dim3(8, 32, 1), dim3(256), 0, stream>>>(
        obf, wcb, bc, bc, bc, out, D_, D_);
}